// Round 5
// baseline (1227.927 us; speedup 1.0000x reference)
//
#include <hip/hip_runtime.h>
#include <math.h>

namespace {

constexpr int Bn = 8192;
constexpr int Dn = 508;
constexpr int Hn = 256;
constexpr int NSTEPS = 8;
constexpr int Kp = 512;  // D padded to 512 (zero-padded on the WEIGHT side)
constexpr float DT = 1.f / NSTEPS;
constexpr float DT6 = DT / 6.f;

typedef __attribute__((ext_vector_type(8))) short short8v;
typedef __attribute__((ext_vector_type(4))) float f32x4;

__device__ __forceinline__ short f2b(float f) {
  union { float f; unsigned u; } v; v.f = f;
  unsigned r = v.u + 0x7fffu + ((v.u >> 16) & 1u);
  return (short)(r >> 16);
}
__device__ __forceinline__ float b2f(short s) {
  union { unsigned u; float f; } v;
  v.u = ((unsigned)(unsigned short)s) << 16;
  return v.f;
}
__device__ __forceinline__ unsigned pk2(short lo, short hi) {
  return ((unsigned)(unsigned short)lo) | (((unsigned)(unsigned short)hi) << 16);
}
__device__ __forceinline__ float upk_lo(unsigned p) {
  union { unsigned u; float f; } v; v.u = p << 16; return v.f;
}
__device__ __forceinline__ float upk_hi(unsigned p) {
  union { unsigned u; float f; } v; v.u = p & 0xffff0000u; return v.f;
}
__device__ __forceinline__ float ftanh(float x) {
  x = fminf(fmaxf(x, -12.f), 12.f);
  const float e = __expf(2.f * x);
  return __fdividef(e - 1.f, e + 1.f);
}

// ---------------- shared 64x64-block MFMA core for SETUP kernels (validated r2)
template <int KT>
__device__ __forceinline__ void gemm_bb(const short* __restrict__ A, int lda,
                                        const short* __restrict__ Bt, int ldb,
                                        int row0, int col0, int lane,
                                        f32x4 acc[2][2]) {
  const int r = lane & 15, g = lane >> 4;
  const short* a0p = A + (size_t)(row0 + r) * lda + g * 8;
  const short* a1p = A + (size_t)(row0 + 16 + r) * lda + g * 8;
  const short* b0p = Bt + (size_t)(col0 + r) * ldb + g * 8;
  const short* b1p = Bt + (size_t)(col0 + 16 + r) * ldb + g * 8;
#pragma unroll
  for (int kt = 0; kt < KT; ++kt) {
    const short8v a0 = *(const short8v*)(a0p + kt * 32);
    const short8v a1 = *(const short8v*)(a1p + kt * 32);
    const short8v b0 = *(const short8v*)(b0p + kt * 32);
    const short8v b1 = *(const short8v*)(b1p + kt * 32);
    acc[0][0] = __builtin_amdgcn_mfma_f32_16x16x32_bf16(a0, b0, acc[0][0], 0, 0, 0);
    acc[0][1] = __builtin_amdgcn_mfma_f32_16x16x32_bf16(a0, b1, acc[0][1], 0, 0, 0);
    acc[1][0] = __builtin_amdgcn_mfma_f32_16x16x32_bf16(a1, b0, acc[1][0], 0, 0, 0);
    acc[1][1] = __builtin_amdgcn_mfma_f32_16x16x32_bf16(a1, b1, acc[1][1], 0, 0, 0);
  }
}

#define GEMM_PROLOGUE()                                     \
  const int tid = threadIdx.x, wid = tid >> 6, lane = tid & 63; \
  const int row0 = blockIdx.y * 64 + (wid >> 1) * 32;       \
  const int col0 = blockIdx.x * 64 + (wid & 1) * 32;        \
  const int rq = (lane >> 4) * 4, cc = lane & 15;           \
  const f32x4 z4 = {0.f, 0.f, 0.f, 0.f};                    \
  f32x4 acc[2][2] = {{z4, z4}, {z4, z4}};

// ---------------- setup kernels (unchanged, validated) ----------------

__global__ __launch_bounds__(256) void k_cast_bf(const float* __restrict__ src, int R,
                                                 int C, short* __restrict__ dst, int ldd) {
  const int total = R * ldd;
  for (int idx = blockIdx.x * 256 + threadIdx.x; idx < total; idx += gridDim.x * 256) {
    const int r = idx / ldd, c = idx - r * ldd;
    dst[idx] = (c < C) ? f2b(src[(size_t)r * C + c]) : (short)0;
  }
}

__global__ __launch_bounds__(256) void k_transpose_bf(const float* __restrict__ src, int K,
                                                      int N, short* __restrict__ dst,
                                                      int Nd, int ldd) {
  const int total = Nd * ldd;
  for (int idx = blockIdx.x * 256 + threadIdx.x; idx < total; idx += gridDim.x * 256) {
    const int n = idx / ldd, k = idx - n * ldd;
    dst[idx] = (k < K && n < N) ? f2b(src[(size_t)k * N + n]) : (short)0;
  }
}

__global__ __launch_bounds__(256) void k_c0(const float* __restrict__ w0,
                                            const float* __restrict__ b2,
                                            float* __restrict__ c0) {
  const int n = threadIdx.x;
  float s = 0.f;
#pragma unroll 8
  for (int d = 0; d < Dn; ++d) s += b2[d] * w0[(size_t)d * Hn + n];
  c0[n] = s;
}

__global__ __launch_bounds__(256) void k_w20t(const short* __restrict__ w0T,
                                              const short* __restrict__ w2b,
                                              short* __restrict__ w20T) {
  GEMM_PROLOGUE();
  gemm_bb<16>(w0T, Kp, w2b, Kp, row0, col0, lane, acc);
#pragma unroll
  for (int i = 0; i < 2; ++i)
#pragma unroll
    for (int j = 0; j < 2; ++j)
#pragma unroll
      for (int q = 0; q < 4; ++q)
        w20T[(size_t)(row0 + i * 16 + rq + q) * Hn + col0 + j * 16 + cc] =
            f2b(acc[i][j][q]);
}

// MODE 0: z = A@B + cond*w0c (f32) ; MODE 1/2: bout = bf16(A@B)
template <int MODE>
__global__ __launch_bounds__(256) void k_ginit(const short* __restrict__ A,
                                               const short* __restrict__ Bt,
                                               const float* __restrict__ cond,
                                               const float* __restrict__ w0c,
                                               float* __restrict__ zout,
                                               short* __restrict__ bout) {
  GEMM_PROLOGUE();
  gemm_bb<16>(A, Bt == nullptr ? Kp : Kp, Bt, Kp, row0, col0, lane, acc);
#pragma unroll
  for (int i = 0; i < 2; ++i)
#pragma unroll
    for (int j = 0; j < 2; ++j)
#pragma unroll
      for (int q = 0; q < 4; ++q) {
        const int row = row0 + i * 16 + rq + q;
        const int col = col0 + j * 16 + cc;
        const size_t idx = (size_t)row * Hn + col;
        if (MODE == 0)
          zout[idx] = acc[i][j][q] + cond[row] * w0c[col];
        else
          bout[idx] = f2b(acc[i][j][q]);
      }
}

// ---------------- the fused ODE kernel ----------------
// Block: 512 threads = 8 waves; 32 batch rows per block; wave w owns the
// 32-col strip [w*32, w*32+32). Grid = 256 blocks = exactly 1 block/CU.
// amdgpu_waves_per_eu(2,2): pin allocator occupancy target to 2 waves/EU so
// it uses the full 256-VGPR budget instead of capping at 128 and spilling
// (r3/r4 showed VGPR=128 + ~650 MB scratch writes with launch_bounds only).

// swizzled short-index into a [32][256] bf16 LDS tile:
// byte ^= ((row&7)<<4)  =>  short idx ^= ((row&7)<<3). Keeps 8-short align.
__device__ __forceinline__ int swz(int row, int col) {
  return (row * 256 + col) ^ ((row & 7) << 3);
}

// acc[rb][nt] += A(32x256, swizzled LDS) @ Bt-strip. Bt row-major [N][256]
// (k contiguous, B^T). Wave covers cols [cb, cb+16*NT).
template <int NT>
__device__ __forceinline__ void gemm2(const short* __restrict__ As,
                                      const short* __restrict__ Bt, int cb,
                                      int cc, int g, f32x4 acc[][NT]) {
  const int kb0 = g * 8;
#pragma unroll
  for (int ks = 0; ks < 8; ++ks) {
    const int k = kb0 + ks * 32;
    const short8v a0 = *(const short8v*)(As + swz(cc, k));
    const short8v a1 = *(const short8v*)(As + swz(cc + 16, k));
#pragma unroll
    for (int nt = 0; nt < NT; ++nt) {
      const short8v b = *(const short8v*)(Bt + (size_t)(cb + nt * 16 + cc) * 256 + k);
      acc[0][nt] = __builtin_amdgcn_mfma_f32_16x16x32_bf16(a0, b, acc[0][nt], 0, 0, 0);
      acc[1][nt] = __builtin_amdgcn_mfma_f32_16x16x32_bf16(a1, b, acc[1][nt], 0, 0, 0);
    }
  }
}

__global__ __attribute__((amdgpu_flat_work_group_size(512, 512)))
__attribute__((amdgpu_waves_per_eu(2, 2))) void k_mega(
    const float* __restrict__ zg, const short* __restrict__ u_g,
    const short* __restrict__ g2_g, const short* __restrict__ w1T,
    const short* __restrict__ w1b, const short* __restrict__ w20T,
    const short* __restrict__ w2T, const float* __restrict__ b0,
    const float* __restrict__ w0t, const float* __restrict__ b1,
    const float* __restrict__ c0, const float* __restrict__ b2,
    const float* __restrict__ x, float* __restrict__ yout,
    float* __restrict__ ldout) {
  __shared__ short h0s[32 * 256];
  __shared__ short h1s[32 * 256];
  __shared__ short g1s[32 * 256];
  __shared__ float red[32][8];

  const int tid = threadIdx.x;
  const int w = tid >> 6, lane = tid & 63;
  const int cc = lane & 15, g = lane >> 4, rq = g * 4;
  const int r0 = blockIdx.x * 32;
  const int cb = w * 32;  // wave's 32-col strip for the H-space GEMMs

  // per-lane column constants (f32)
  float b0c[2], w0tc[2], b1c[2], c0c[2];
#pragma unroll
  for (int nt = 0; nt < 2; ++nt) {
    const int col = cb + nt * 16 + cc;
    b0c[nt] = b0[col];
    w0tc[nt] = w0t[col];
    b1c[nt] = b1[col];
    c0c[nt] = c0[col];
  }

  // persistent per-thread state (C-fragment layout:
  // row = r0 + rb*16 + rq + q, col = cb + nt*16 + cc)
  float z_[2][2][4], kza[2][2][4], kzp[2][2][4], hs[2][2][4];
  unsigned u_pk[2][2][2], g2_pk[2][2][2];  // bf16 pairs packed along q
  float tr_[2][4];
#pragma unroll
  for (int rb = 0; rb < 2; ++rb)
#pragma unroll
    for (int nt = 0; nt < 2; ++nt) {
      const size_t i0 = (size_t)(r0 + rb * 16 + rq) * Hn + cb + nt * 16 + cc;
#pragma unroll
      for (int q = 0; q < 4; ++q) {
        z_[rb][nt][q] = zg[i0 + (size_t)q * Hn];
        kzp[rb][nt][q] = 0.f;
        hs[rb][nt][q] = 0.f;
      }
      u_pk[rb][nt][0] = pk2(u_g[i0], u_g[i0 + Hn]);
      u_pk[rb][nt][1] = pk2(u_g[i0 + 2 * Hn], u_g[i0 + 3 * Hn]);
      g2_pk[rb][nt][0] = pk2(g2_g[i0], g2_g[i0 + Hn]);
      g2_pk[rb][nt][1] = pk2(g2_g[i0 + 2 * Hn], g2_g[i0 + 3 * Hn]);
    }
#pragma unroll
  for (int rb = 0; rb < 2; ++rb)
#pragma unroll
    for (int q = 0; q < 4; ++q) tr_[rb][q] = 0.f;

  constexpr float offs[4] = {0.f, 0.5f, 0.5f, 1.f};
  constexpr float alph[4] = {0.f, 0.5f * DT, 0.5f * DT, DT};
  constexpr float mlt[4] = {1.f, 2.f, 2.f, 1.f};
  const f32x4 zero4 = {0.f, 0.f, 0.f, 0.f};

  for (int s = 0; s < NSTEPS; ++s) {
#pragma unroll
    for (int j = 0; j < 4; ++j) {
      const float tval = ((float)s + offs[j]) * DT;
      // ---- A: h0 = tanh(z + a*kzp + b0 + t*w0t)  (m0 recomputed in D)
#pragma unroll
      for (int rb = 0; rb < 2; ++rb)
#pragma unroll
        for (int nt = 0; nt < 2; ++nt)
#pragma unroll
          for (int q = 0; q < 4; ++q) {
            const float pre =
                z_[rb][nt][q] + alph[j] * kzp[rb][nt][q] + b0c[nt] + tval * w0tc[nt];
            h0s[swz(rb * 16 + rq + q, cb + nt * 16 + cc)] = f2b(ftanh(pre));
          }
      __syncthreads();
      // ---- B: h1 = tanh(h0@w1 + b1); g1 = g2*(1-h1^2); hs += mlt*h1
      {
        f32x4 acc[2][2] = {{zero4, zero4}, {zero4, zero4}};
        gemm2<2>(h0s, w1T, cb, cc, g, acc);
#pragma unroll
        for (int rb = 0; rb < 2; ++rb)
#pragma unroll
          for (int nt = 0; nt < 2; ++nt)
#pragma unroll
            for (int q = 0; q < 4; ++q) {
              const float v = ftanh(acc[rb][nt][q] + b1c[nt]);
              const float g2q = (q & 1) ? upk_hi(g2_pk[rb][nt][q >> 1])
                                        : upk_lo(g2_pk[rb][nt][q >> 1]);
              const int si = swz(rb * 16 + rq + q, cb + nt * 16 + cc);
              h1s[si] = f2b(v);
              g1s[si] = f2b(g2q * (1.f - v * v));
              hs[rb][nt][q] += mlt[j] * v;
            }
      }
      __syncthreads();
      // ---- C: kz = h1@w20 + c0 ; RK4 z-state update
      {
        f32x4 acc[2][2] = {{zero4, zero4}, {zero4, zero4}};
        gemm2<2>(h1s, w20T, cb, cc, g, acc);
#pragma unroll
        for (int rb = 0; rb < 2; ++rb)
#pragma unroll
          for (int nt = 0; nt < 2; ++nt)
#pragma unroll
            for (int q = 0; q < 4; ++q) {
              const float kzv = acc[rb][nt][q] + c0c[nt];
              if (j == 0)
                kza[rb][nt][q] = kzv;
              else
                kza[rb][nt][q] += mlt[j] * kzv;
              if (j < 3)
                kzp[rb][nt][q] = kzv;
              else
                z_[rb][nt][q] += DT6 * kza[rb][nt][q];
            }
      }
      // ---- D: trace: (g1@w1^T) . ((1-h0^2)*u), accumulated per row
      {
        f32x4 acc[2][2] = {{zero4, zero4}, {zero4, zero4}};
        gemm2<2>(g1s, w1b, cb, cc, g, acc);
#pragma unroll
        for (int rb = 0; rb < 2; ++rb)
#pragma unroll
          for (int q = 0; q < 4; ++q) {
            float sq = 0.f;
#pragma unroll
            for (int nt = 0; nt < 2; ++nt) {
              const float h0v =
                  b2f(h0s[swz(rb * 16 + rq + q, cb + nt * 16 + cc)]);
              const float uq = (q & 1) ? upk_hi(u_pk[rb][nt][q >> 1])
                                       : upk_lo(u_pk[rb][nt][q >> 1]);
              sq += acc[rb][nt][q] * (1.f - h0v * h0v) * uq;
            }
            tr_[rb][q] += (DT6 * mlt[j]) * sq;
          }
      }
      __syncthreads();
    }
  }

  // ---- final: y = x + DT6 * HS@w2 + b2  (sum of dt*b2 over 8 steps = b2)
#pragma unroll
  for (int rb = 0; rb < 2; ++rb)
#pragma unroll
    for (int nt = 0; nt < 2; ++nt)
#pragma unroll
      for (int q = 0; q < 4; ++q)
        h0s[swz(rb * 16 + rq + q, cb + nt * 16 + cc)] = f2b(hs[rb][nt][q]);
  __syncthreads();
  {
    f32x4 facc[2][4] = {{zero4, zero4, zero4, zero4}, {zero4, zero4, zero4, zero4}};
    gemm2<4>(h0s, w2T, w * 64, cc, g, facc);
#pragma unroll
    for (int rb = 0; rb < 2; ++rb)
#pragma unroll
      for (int nt = 0; nt < 4; ++nt) {
        const int col = w * 64 + nt * 16 + cc;
        if (col < Dn) {
          const float b2c = b2[col];
#pragma unroll
          for (int q = 0; q < 4; ++q) {
            const size_t ix = (size_t)(r0 + rb * 16 + rq + q) * Dn + col;
            yout[ix] = x[ix] + DT6 * facc[rb][nt][q] + b2c;
          }
        }
      }
  }

  // ---- trace reduction: over the 16 cc-lanes, then over 8 waves
#pragma unroll
  for (int rb = 0; rb < 2; ++rb)
#pragma unroll
    for (int q = 0; q < 4; ++q) {
      float v = tr_[rb][q];
      v += __shfl_xor(v, 1);
      v += __shfl_xor(v, 2);
      v += __shfl_xor(v, 4);
      v += __shfl_xor(v, 8);
      if (cc == 0) red[rb * 16 + rq + q][w] = v;
    }
  __syncthreads();
  if (tid < 32) {
    float t = 0.f;
#pragma unroll
    for (int ww = 0; ww < 8; ++ww) t += red[tid][ww];
    ldout[r0 + tid] = t;
  }
}

}  // namespace

extern "C" void kernel_launch(void* const* d_in, const int* in_sizes, int n_in,
                              void* d_out, int out_size, void* d_ws, size_t ws_size,
                              hipStream_t stream) {
  const float* x = (const float*)d_in[0];
  const float* cond = (const float*)d_in[1];
  const float* eps = (const float*)d_in[2];
  const float* w0 = (const float*)d_in[3];
  const float* b0 = (const float*)d_in[4];
  const float* w1 = (const float*)d_in[5];
  const float* b1 = (const float*)d_in[6];
  const float* w2 = (const float*)d_in[7];
  const float* b2 = (const float*)d_in[8];
  const float* w0c = w0 + (size_t)508 * Hn;  // cond row
  const float* w0t = w0 + (size_t)509 * Hn;  // time row

  const size_t BD = (size_t)Bn * Dn, BH = (size_t)Bn * Hn, BKp = (size_t)Bn * Kp;
  char* p = (char*)d_ws;
  auto alloc_f = [&](size_t n) { float* r = (float*)p; p += n * 4; return r; };
  auto alloc_s = [&](size_t n) { short* r = (short*)p; p += ((n * 2 + 15) & ~15ull); return r; };

  float* zg = alloc_f(BH);
  float* c0 = alloc_f(256);
  short* xp = alloc_s(BKp);
  short* epsp = alloc_s(BKp);
  short* u_g = alloc_s(BH);
  short* g2_g = alloc_s(BH);
  short* w0T = alloc_s(256 * 512);
  short* w1T = alloc_s(256 * 256);
  short* w1b = alloc_s(256 * 256);
  short* w2b = alloc_s(256 * 512);
  short* w2T = alloc_s(512 * 256);
  short* w20T = alloc_s(256 * 256);

  float* yout = (float*)d_out;        // [B, D]
  float* ldout = (float*)d_out + BD;  // [B]

  const dim3 blk(256);
  const dim3 gH(Hn / 64, Bn / 64);  // (4,128)
  const dim3 gW(4, 4);

  // ---- setup (weights + z/u/g2 precompute) ----
  k_cast_bf<<<4096, blk, 0, stream>>>(x, Bn, Dn, xp, Kp);
  k_cast_bf<<<4096, blk, 0, stream>>>(eps, Bn, Dn, epsp, Kp);
  k_cast_bf<<<256, blk, 0, stream>>>(w1, Hn, Hn, w1b, Hn);
  k_cast_bf<<<512, blk, 0, stream>>>(w2, Hn, Dn, w2b, Kp);
  k_transpose_bf<<<256, blk, 0, stream>>>(w1, Hn, Hn, w1T, Hn, Hn);
  k_transpose_bf<<<512, blk, 0, stream>>>(w0, Dn, Hn, w0T, Hn, Kp);
  k_transpose_bf<<<512, blk, 0, stream>>>(w2, Hn, Dn, w2T, Kp, Hn);
  k_c0<<<1, blk, 0, stream>>>(w0, b2, c0);
  k_w20t<<<gW, blk, 0, stream>>>(w0T, w2b, w20T);
  k_ginit<0><<<gH, blk, 0, stream>>>(xp, w0T, cond, w0c, zg, nullptr);
  k_ginit<1><<<gH, blk, 0, stream>>>(epsp, w0T, nullptr, nullptr, nullptr, u_g);
  k_ginit<2><<<gH, blk, 0, stream>>>(epsp, w2b, nullptr, nullptr, nullptr, g2_g);

  // ---- the whole ODE in one kernel ----
  k_mega<<<dim3(Bn / 32), dim3(512), 0, stream>>>(zg, u_g, g2_g, w1T, w1b, w20T,
                                                  w2T, b0, w0t, b1, c0, b2, x,
                                                  yout, ldout);
}

// Round 6
// 1213.163 us; speedup vs baseline: 1.0122x; 1.0122x over previous
//
#include <hip/hip_runtime.h>
#include <math.h>

namespace {

constexpr int Bn = 8192;
constexpr int Dn = 508;
constexpr int Hn = 256;
constexpr int NSTEPS = 8;
constexpr int Kp = 512;  // D padded to 512 (zero-padded on the WEIGHT side)
constexpr float DT = 1.f / NSTEPS;
constexpr float DT6 = DT / 6.f;

typedef __attribute__((ext_vector_type(8))) short short8v;
typedef __attribute__((ext_vector_type(4))) float f32x4;

__device__ __forceinline__ short f2b(float f) {
  union { float f; unsigned u; } v; v.f = f;
  unsigned r = v.u + 0x7fffu + ((v.u >> 16) & 1u);
  return (short)(r >> 16);
}
__device__ __forceinline__ float b2f(short s) {
  union { unsigned u; float f; } v;
  v.u = ((unsigned)(unsigned short)s) << 16;
  return v.f;
}
__device__ __forceinline__ float ftanh(float x) {
  x = fminf(fmaxf(x, -12.f), 12.f);
  const float e = __expf(2.f * x);
  return __fdividef(e - 1.f, e + 1.f);
}

// ---------------- shared 64x64-block MFMA core for SETUP kernels (validated r2)
template <int KT>
__device__ __forceinline__ void gemm_bb(const short* __restrict__ A, int lda,
                                        const short* __restrict__ Bt, int ldb,
                                        int row0, int col0, int lane,
                                        f32x4 acc[2][2]) {
  const int r = lane & 15, g = lane >> 4;
  const short* a0p = A + (size_t)(row0 + r) * lda + g * 8;
  const short* a1p = A + (size_t)(row0 + 16 + r) * lda + g * 8;
  const short* b0p = Bt + (size_t)(col0 + r) * ldb + g * 8;
  const short* b1p = Bt + (size_t)(col0 + 16 + r) * ldb + g * 8;
#pragma unroll
  for (int kt = 0; kt < KT; ++kt) {
    const short8v a0 = *(const short8v*)(a0p + kt * 32);
    const short8v a1 = *(const short8v*)(a1p + kt * 32);
    const short8v b0 = *(const short8v*)(b0p + kt * 32);
    const short8v b1 = *(const short8v*)(b1p + kt * 32);
    acc[0][0] = __builtin_amdgcn_mfma_f32_16x16x32_bf16(a0, b0, acc[0][0], 0, 0, 0);
    acc[0][1] = __builtin_amdgcn_mfma_f32_16x16x32_bf16(a0, b1, acc[0][1], 0, 0, 0);
    acc[1][0] = __builtin_amdgcn_mfma_f32_16x16x32_bf16(a1, b0, acc[1][0], 0, 0, 0);
    acc[1][1] = __builtin_amdgcn_mfma_f32_16x16x32_bf16(a1, b1, acc[1][1], 0, 0, 0);
  }
}

#define GEMM_PROLOGUE()                                     \
  const int tid = threadIdx.x, wid = tid >> 6, lane = tid & 63; \
  const int row0 = blockIdx.y * 64 + (wid >> 1) * 32;       \
  const int col0 = blockIdx.x * 64 + (wid & 1) * 32;        \
  const int rq = (lane >> 4) * 4, cc = lane & 15;           \
  const f32x4 z4 = {0.f, 0.f, 0.f, 0.f};                    \
  f32x4 acc[2][2] = {{z4, z4}, {z4, z4}};

// ---------------- setup kernels (unchanged, validated) ----------------

__global__ __launch_bounds__(256) void k_cast_bf(const float* __restrict__ src, int R,
                                                 int C, short* __restrict__ dst, int ldd) {
  const int total = R * ldd;
  for (int idx = blockIdx.x * 256 + threadIdx.x; idx < total; idx += gridDim.x * 256) {
    const int r = idx / ldd, c = idx - r * ldd;
    dst[idx] = (c < C) ? f2b(src[(size_t)r * C + c]) : (short)0;
  }
}

__global__ __launch_bounds__(256) void k_transpose_bf(const float* __restrict__ src, int K,
                                                      int N, short* __restrict__ dst,
                                                      int Nd, int ldd) {
  const int total = Nd * ldd;
  for (int idx = blockIdx.x * 256 + threadIdx.x; idx < total; idx += gridDim.x * 256) {
    const int n = idx / ldd, k = idx - n * ldd;
    dst[idx] = (k < K && n < N) ? f2b(src[(size_t)k * N + n]) : (short)0;
  }
}

__global__ __launch_bounds__(256) void k_c0(const float* __restrict__ w0,
                                            const float* __restrict__ b2,
                                            float* __restrict__ c0) {
  const int n = threadIdx.x;
  float s = 0.f;
#pragma unroll 8
  for (int d = 0; d < Dn; ++d) s += b2[d] * w0[(size_t)d * Hn + n];
  c0[n] = s;
}

__global__ __launch_bounds__(256) void k_w20t(const short* __restrict__ w0T,
                                              const short* __restrict__ w2b,
                                              short* __restrict__ w20T) {
  GEMM_PROLOGUE();
  gemm_bb<16>(w0T, Kp, w2b, Kp, row0, col0, lane, acc);
#pragma unroll
  for (int i = 0; i < 2; ++i)
#pragma unroll
    for (int j = 0; j < 2; ++j)
#pragma unroll
      for (int q = 0; q < 4; ++q)
        w20T[(size_t)(row0 + i * 16 + rq + q) * Hn + col0 + j * 16 + cc] =
            f2b(acc[i][j][q]);
}

// MODE 0: z = A@B + cond*w0c (f32) ; MODE 1/2: bout = bf16(A@B)
template <int MODE>
__global__ __launch_bounds__(256) void k_ginit(const short* __restrict__ A,
                                               const short* __restrict__ Bt,
                                               const float* __restrict__ cond,
                                               const float* __restrict__ w0c,
                                               float* __restrict__ zout,
                                               short* __restrict__ bout) {
  GEMM_PROLOGUE();
  gemm_bb<16>(A, Kp, Bt, Kp, row0, col0, lane, acc);
#pragma unroll
  for (int i = 0; i < 2; ++i)
#pragma unroll
    for (int j = 0; j < 2; ++j)
#pragma unroll
      for (int q = 0; q < 4; ++q) {
        const int row = row0 + i * 16 + rq + q;
        const int col = col0 + j * 16 + cc;
        const size_t idx = (size_t)row * Hn + col;
        if (MODE == 0)
          zout[idx] = acc[i][j][q] + cond[row] * w0c[col];
        else
          bout[idx] = f2b(acc[i][j][q]);
      }
}

// ---------------- the fused ODE kernel ----------------
// 512 threads = 8 waves; 32 batch rows per block; wave w owns col-strip
// [w*32, w*32+32). Grid = 256 = 1 block/CU. Register budget is the hard
// constraint: the backend pins this kernel at 128 VGPRs (default 4 waves/EU;
// waves_per_eu attr was ignored in r5), so ALL state must fit under 128:
//  - hs accumulator lives in LDS f32 [32][258] (pad -> conflict-free)
//  - u/g2 are re-read from global (L2-resident 16KB/block slices) at use site
//  - RK4 j-loop is NOT unrolled (small scheduler window -> low transient peak)

// swizzled short-index into a [32][256] bf16 LDS tile:
// byte ^= ((row&7)<<4)  =>  short idx ^= ((row&7)<<3). Keeps 8-short align.
__device__ __forceinline__ int swz(int row, int col) {
  return (row * 256 + col) ^ ((row & 7) << 3);
}

// acc[rb][nt] += A(32x256, swizzled LDS) @ Bt-strip. Bt row-major [N][256]
// (k contiguous, B^T). Wave covers cols [cb, cb+16*NT).
template <int NT>
__device__ __forceinline__ void gemm2(const short* __restrict__ As,
                                      const short* __restrict__ Bt, int cb,
                                      int cc, int g, f32x4 acc[][NT]) {
  const int kb0 = g * 8;
#pragma unroll
  for (int ks = 0; ks < 8; ++ks) {
    const int k = kb0 + ks * 32;
    const short8v a0 = *(const short8v*)(As + swz(cc, k));
    const short8v a1 = *(const short8v*)(As + swz(cc + 16, k));
#pragma unroll
    for (int nt = 0; nt < NT; ++nt) {
      const short8v b = *(const short8v*)(Bt + (size_t)(cb + nt * 16 + cc) * 256 + k);
      acc[0][nt] = __builtin_amdgcn_mfma_f32_16x16x32_bf16(a0, b, acc[0][nt], 0, 0, 0);
      acc[1][nt] = __builtin_amdgcn_mfma_f32_16x16x32_bf16(a1, b, acc[1][nt], 0, 0, 0);
    }
  }
}

constexpr int HP = 258;  // padded f32 row stride for hsum LDS

__global__ __launch_bounds__(512) void k_mega(
    const float* __restrict__ zg, const short* __restrict__ u_g,
    const short* __restrict__ g2_g, const short* __restrict__ w1T,
    const short* __restrict__ w1b, const short* __restrict__ w20T,
    const short* __restrict__ w2T, const float* __restrict__ b0,
    const float* __restrict__ w0t, const float* __restrict__ b1,
    const float* __restrict__ c0, const float* __restrict__ b2,
    const float* __restrict__ x, float* __restrict__ yout,
    float* __restrict__ ldout) {
  __shared__ short h0s[32 * 256];
  __shared__ short h1s[32 * 256];
  __shared__ short g1s[32 * 256];
  __shared__ float hsum[32 * HP];
  __shared__ float red[32][8];

  const int tid = threadIdx.x;
  const int w = tid >> 6, lane = tid & 63;
  const int cc = lane & 15, g = lane >> 4, rq = g * 4;
  const int r0 = blockIdx.x * 32;
  const int cb = w * 32;  // wave's 32-col strip for the H-space GEMMs

  // per-lane column constants (f32)
  float b0c[2], w0tc[2], b1c[2], c0c[2];
#pragma unroll
  for (int nt = 0; nt < 2; ++nt) {
    const int col = cb + nt * 16 + cc;
    b0c[nt] = b0[col];
    w0tc[nt] = w0t[col];
    b1c[nt] = b1[col];
    c0c[nt] = c0[col];
  }

  // global base for this thread's fragment elements:
  // element (rb,nt,q) lives at gbase + rb*16*Hn + q*Hn + nt*16
  const size_t gbase = (size_t)(r0 + rq) * Hn + cb + cc;

  // persistent per-thread register state (C-fragment layout)
  float z_[2][2][4], kza[2][2][4], kzp[2][2][4];
  float tr_[2][4];
#pragma unroll
  for (int rb = 0; rb < 2; ++rb)
#pragma unroll
    for (int nt = 0; nt < 2; ++nt)
#pragma unroll
      for (int q = 0; q < 4; ++q) {
        z_[rb][nt][q] = zg[gbase + (size_t)(rb * 16 + q) * Hn + nt * 16];
        kzp[rb][nt][q] = 0.f;
      }
#pragma unroll
  for (int rb = 0; rb < 2; ++rb)
#pragma unroll
    for (int q = 0; q < 4; ++q) tr_[rb][q] = 0.f;

  for (int i = tid; i < 32 * HP; i += 512) hsum[i] = 0.f;

  const f32x4 zero4 = {0.f, 0.f, 0.f, 0.f};

  for (int e = 0; e < 4 * NSTEPS; ++e) {
    const int j = e & 3, s = e >> 2;
    const float oj = (j == 0) ? 0.f : ((j == 3) ? 1.f : 0.5f);
    const float aj = (j == 0) ? 0.f : ((j == 3) ? DT : 0.5f * DT);
    const float mj = (j == 1 || j == 2) ? 2.f : 1.f;
    const float tval = ((float)s + oj) * DT;

    // ---- A: h0 = tanh(z + aj*kzp + b0 + t*w0t)
#pragma unroll
    for (int rb = 0; rb < 2; ++rb)
#pragma unroll
      for (int nt = 0; nt < 2; ++nt)
#pragma unroll
        for (int q = 0; q < 4; ++q) {
          const float pre =
              z_[rb][nt][q] + aj * kzp[rb][nt][q] + b0c[nt] + tval * w0tc[nt];
          h0s[swz(rb * 16 + rq + q, cb + nt * 16 + cc)] = f2b(ftanh(pre));
        }
    __syncthreads();

    // ---- B: h1 = tanh(h0@w1 + b1); g1 = g2*(1-h1^2); hsum += mj*h1
    {
      f32x4 acc[2][2] = {{zero4, zero4}, {zero4, zero4}};
      gemm2<2>(h0s, w1T, cb, cc, g, acc);
#pragma unroll
      for (int rb = 0; rb < 2; ++rb)
#pragma unroll
        for (int nt = 0; nt < 2; ++nt)
#pragma unroll
          for (int q = 0; q < 4; ++q) {
            const float v = ftanh(acc[rb][nt][q] + b1c[nt]);
            const float g2q =
                b2f(g2_g[gbase + (size_t)(rb * 16 + q) * Hn + nt * 16]);
            const int si = swz(rb * 16 + rq + q, cb + nt * 16 + cc);
            h1s[si] = f2b(v);
            g1s[si] = f2b(g2q * (1.f - v * v));
            hsum[(rb * 16 + rq + q) * HP + cb + nt * 16 + cc] += mj * v;
          }
    }
    __syncthreads();

    // ---- C: kz = h1@w20 + c0 ; RK4 z-state update
    {
      f32x4 acc[2][2] = {{zero4, zero4}, {zero4, zero4}};
      gemm2<2>(h1s, w20T, cb, cc, g, acc);
#pragma unroll
      for (int rb = 0; rb < 2; ++rb)
#pragma unroll
        for (int nt = 0; nt < 2; ++nt)
#pragma unroll
          for (int q = 0; q < 4; ++q) {
            const float kzv = acc[rb][nt][q] + c0c[nt];
            if (j == 0)
              kza[rb][nt][q] = kzv;
            else
              kza[rb][nt][q] += mj * kzv;
            if (j < 3)
              kzp[rb][nt][q] = kzv;
            else
              z_[rb][nt][q] += DT6 * kza[rb][nt][q];
          }
    }

    // ---- D: trace: (g1@w1^T) . ((1-h0^2)*u), accumulated per row
    {
      f32x4 acc[2][2] = {{zero4, zero4}, {zero4, zero4}};
      gemm2<2>(g1s, w1b, cb, cc, g, acc);
#pragma unroll
      for (int rb = 0; rb < 2; ++rb)
#pragma unroll
        for (int q = 0; q < 4; ++q) {
          float sq = 0.f;
#pragma unroll
          for (int nt = 0; nt < 2; ++nt) {
            const float h0v = b2f(h0s[swz(rb * 16 + rq + q, cb + nt * 16 + cc)]);
            const float uq =
                b2f(u_g[gbase + (size_t)(rb * 16 + q) * Hn + nt * 16]);
            sq += acc[rb][nt][q] * (1.f - h0v * h0v) * uq;
          }
          tr_[rb][q] += (DT6 * mj) * sq;
        }
    }
    __syncthreads();
  }

  // ---- final: y = x + DT6 * HS@w2 + b2  (sum of dt*b2 over 8 steps = b2)
#pragma unroll
  for (int rb = 0; rb < 2; ++rb)
#pragma unroll
    for (int nt = 0; nt < 2; ++nt)
#pragma unroll
      for (int q = 0; q < 4; ++q)
        h0s[swz(rb * 16 + rq + q, cb + nt * 16 + cc)] =
            f2b(hsum[(rb * 16 + rq + q) * HP + cb + nt * 16 + cc]);
  __syncthreads();
  {
    f32x4 facc[2][4] = {{zero4, zero4, zero4, zero4}, {zero4, zero4, zero4, zero4}};
    gemm2<4>(h0s, w2T, w * 64, cc, g, facc);
#pragma unroll
    for (int rb = 0; rb < 2; ++rb)
#pragma unroll
      for (int nt = 0; nt < 4; ++nt) {
        const int col = w * 64 + nt * 16 + cc;
        if (col < Dn) {
          const float b2c = b2[col];
#pragma unroll
          for (int q = 0; q < 4; ++q) {
            const size_t ix = (size_t)(r0 + rb * 16 + rq + q) * Dn + col;
            yout[ix] = x[ix] + DT6 * facc[rb][nt][q] + b2c;
          }
        }
      }
  }

  // ---- trace reduction: over the 16 cc-lanes, then over 8 waves
#pragma unroll
  for (int rb = 0; rb < 2; ++rb)
#pragma unroll
    for (int q = 0; q < 4; ++q) {
      float v = tr_[rb][q];
      v += __shfl_xor(v, 1);
      v += __shfl_xor(v, 2);
      v += __shfl_xor(v, 4);
      v += __shfl_xor(v, 8);
      if (cc == 0) red[rb * 16 + rq + q][w] = v;
    }
  __syncthreads();
  if (tid < 32) {
    float t = 0.f;
#pragma unroll
    for (int ww = 0; ww < 8; ++ww) t += red[tid][ww];
    ldout[r0 + tid] = t;
  }
}

}  // namespace

extern "C" void kernel_launch(void* const* d_in, const int* in_sizes, int n_in,
                              void* d_out, int out_size, void* d_ws, size_t ws_size,
                              hipStream_t stream) {
  const float* x = (const float*)d_in[0];
  const float* cond = (const float*)d_in[1];
  const float* eps = (const float*)d_in[2];
  const float* w0 = (const float*)d_in[3];
  const float* b0 = (const float*)d_in[4];
  const float* w1 = (const float*)d_in[5];
  const float* b1 = (const float*)d_in[6];
  const float* w2 = (const float*)d_in[7];
  const float* b2 = (const float*)d_in[8];
  const float* w0c = w0 + (size_t)508 * Hn;  // cond row
  const float* w0t = w0 + (size_t)509 * Hn;  // time row

  const size_t BD = (size_t)Bn * Dn, BH = (size_t)Bn * Hn, BKp = (size_t)Bn * Kp;
  char* p = (char*)d_ws;
  auto alloc_f = [&](size_t n) { float* r = (float*)p; p += n * 4; return r; };
  auto alloc_s = [&](size_t n) { short* r = (short*)p; p += ((n * 2 + 15) & ~15ull); return r; };

  float* zg = alloc_f(BH);
  float* c0 = alloc_f(256);
  short* xp = alloc_s(BKp);
  short* epsp = alloc_s(BKp);
  short* u_g = alloc_s(BH);
  short* g2_g = alloc_s(BH);
  short* w0T = alloc_s(256 * 512);
  short* w1T = alloc_s(256 * 256);
  short* w1b = alloc_s(256 * 256);
  short* w2b = alloc_s(256 * 512);
  short* w2T = alloc_s(512 * 256);
  short* w20T = alloc_s(256 * 256);

  float* yout = (float*)d_out;        // [B, D]
  float* ldout = (float*)d_out + BD;  // [B]

  const dim3 blk(256);
  const dim3 gH(Hn / 64, Bn / 64);  // (4,128)
  const dim3 gW(4, 4);

  // ---- setup (weights + z/u/g2 precompute) ----
  k_cast_bf<<<4096, blk, 0, stream>>>(x, Bn, Dn, xp, Kp);
  k_cast_bf<<<4096, blk, 0, stream>>>(eps, Bn, Dn, epsp, Kp);
  k_cast_bf<<<256, blk, 0, stream>>>(w1, Hn, Hn, w1b, Hn);
  k_cast_bf<<<512, blk, 0, stream>>>(w2, Hn, Dn, w2b, Kp);
  k_transpose_bf<<<256, blk, 0, stream>>>(w1, Hn, Hn, w1T, Hn, Hn);
  k_transpose_bf<<<512, blk, 0, stream>>>(w0, Dn, Hn, w0T, Hn, Kp);
  k_transpose_bf<<<512, blk, 0, stream>>>(w2, Hn, Dn, w2T, Kp, Hn);
  k_c0<<<1, blk, 0, stream>>>(w0, b2, c0);
  k_w20t<<<gW, blk, 0, stream>>>(w0T, w2b, w20T);
  k_ginit<0><<<gH, blk, 0, stream>>>(xp, w0T, cond, w0c, zg, nullptr);
  k_ginit<1><<<gH, blk, 0, stream>>>(epsp, w0T, nullptr, nullptr, nullptr, u_g);
  k_ginit<2><<<gH, blk, 0, stream>>>(epsp, w2b, nullptr, nullptr, nullptr, g2_g);

  // ---- the whole ODE in one kernel ----
  k_mega<<<dim3(Bn / 32), dim3(512), 0, stream>>>(zg, u_g, g2_g, w1T, w1b, w20T,
                                                  w2T, b0, w0t, b1, c0, b2, x,
                                                  yout, ldout);
}

// Round 7
// 870.728 us; speedup vs baseline: 1.4102x; 1.3933x over previous
//
#include <hip/hip_runtime.h>
#include <math.h>

namespace {

constexpr int Bn = 8192;
constexpr int Dn = 508;
constexpr int Hn = 256;
constexpr int NSTEPS = 8;
constexpr int Kp = 512;  // D padded to 512 (zero-padded on the WEIGHT side)
constexpr float DT = 1.f / NSTEPS;
constexpr float DT6 = DT / 6.f;

typedef __attribute__((ext_vector_type(8))) short short8v;
typedef __attribute__((ext_vector_type(4))) float f32x4;

__device__ __forceinline__ short f2b(float f) {
  union { float f; unsigned u; } v; v.f = f;
  unsigned r = v.u + 0x7fffu + ((v.u >> 16) & 1u);
  return (short)(r >> 16);
}
__device__ __forceinline__ float b2f(short s) {
  union { unsigned u; float f; } v;
  v.u = ((unsigned)(unsigned short)s) << 16;
  return v.f;
}
__device__ __forceinline__ unsigned pk2(short lo, short hi) {
  return ((unsigned)(unsigned short)lo) | (((unsigned)(unsigned short)hi) << 16);
}
__device__ __forceinline__ float upk_lo(unsigned p) {
  union { unsigned u; float f; } v; v.u = p << 16; return v.f;
}
__device__ __forceinline__ float upk_hi(unsigned p) {
  union { unsigned u; float f; } v; v.u = p & 0xffff0000u; return v.f;
}
__device__ __forceinline__ float ftanh(float x) {
  x = fminf(fmaxf(x, -12.f), 12.f);
  const float e = __expf(2.f * x);
  return __fdividef(e - 1.f, e + 1.f);
}

// ---------------- shared 64x64-block MFMA core for SETUP kernels (validated r2)
template <int KT>
__device__ __forceinline__ void gemm_bb(const short* __restrict__ A, int lda,
                                        const short* __restrict__ Bt, int ldb,
                                        int row0, int col0, int lane,
                                        f32x4 acc[2][2]) {
  const int r = lane & 15, g = lane >> 4;
  const short* a0p = A + (size_t)(row0 + r) * lda + g * 8;
  const short* a1p = A + (size_t)(row0 + 16 + r) * lda + g * 8;
  const short* b0p = Bt + (size_t)(col0 + r) * ldb + g * 8;
  const short* b1p = Bt + (size_t)(col0 + 16 + r) * ldb + g * 8;
#pragma unroll
  for (int kt = 0; kt < KT; ++kt) {
    const short8v a0 = *(const short8v*)(a0p + kt * 32);
    const short8v a1 = *(const short8v*)(a1p + kt * 32);
    const short8v b0 = *(const short8v*)(b0p + kt * 32);
    const short8v b1 = *(const short8v*)(b1p + kt * 32);
    acc[0][0] = __builtin_amdgcn_mfma_f32_16x16x32_bf16(a0, b0, acc[0][0], 0, 0, 0);
    acc[0][1] = __builtin_amdgcn_mfma_f32_16x16x32_bf16(a0, b1, acc[0][1], 0, 0, 0);
    acc[1][0] = __builtin_amdgcn_mfma_f32_16x16x32_bf16(a1, b0, acc[1][0], 0, 0, 0);
    acc[1][1] = __builtin_amdgcn_mfma_f32_16x16x32_bf16(a1, b1, acc[1][1], 0, 0, 0);
  }
}

#define GEMM_PROLOGUE()                                     \
  const int tid = threadIdx.x, wid = tid >> 6, lane = tid & 63; \
  const int row0 = blockIdx.y * 64 + (wid >> 1) * 32;       \
  const int col0 = blockIdx.x * 64 + (wid & 1) * 32;        \
  const int rq = (lane >> 4) * 4, cc = lane & 15;           \
  const f32x4 z4 = {0.f, 0.f, 0.f, 0.f};                    \
  f32x4 acc[2][2] = {{z4, z4}, {z4, z4}};

// ---------------- setup kernels (unchanged, validated) ----------------

__global__ __launch_bounds__(256) void k_cast_bf(const float* __restrict__ src, int R,
                                                 int C, short* __restrict__ dst, int ldd) {
  const int total = R * ldd;
  for (int idx = blockIdx.x * 256 + threadIdx.x; idx < total; idx += gridDim.x * 256) {
    const int r = idx / ldd, c = idx - r * ldd;
    dst[idx] = (c < C) ? f2b(src[(size_t)r * C + c]) : (short)0;
  }
}

__global__ __launch_bounds__(256) void k_transpose_bf(const float* __restrict__ src, int K,
                                                      int N, short* __restrict__ dst,
                                                      int Nd, int ldd) {
  const int total = Nd * ldd;
  for (int idx = blockIdx.x * 256 + threadIdx.x; idx < total; idx += gridDim.x * 256) {
    const int n = idx / ldd, k = idx - n * ldd;
    dst[idx] = (k < K && n < N) ? f2b(src[(size_t)k * N + n]) : (short)0;
  }
}

__global__ __launch_bounds__(256) void k_c0(const float* __restrict__ w0,
                                            const float* __restrict__ b2,
                                            float* __restrict__ c0) {
  const int n = threadIdx.x;
  float s = 0.f;
#pragma unroll 8
  for (int d = 0; d < Dn; ++d) s += b2[d] * w0[(size_t)d * Hn + n];
  c0[n] = s;
}

__global__ __launch_bounds__(256) void k_w20t(const short* __restrict__ w0T,
                                              const short* __restrict__ w2b,
                                              short* __restrict__ w20T) {
  GEMM_PROLOGUE();
  gemm_bb<16>(w0T, Kp, w2b, Kp, row0, col0, lane, acc);
#pragma unroll
  for (int i = 0; i < 2; ++i)
#pragma unroll
    for (int j = 0; j < 2; ++j)
#pragma unroll
      for (int q = 0; q < 4; ++q)
        w20T[(size_t)(row0 + i * 16 + rq + q) * Hn + col0 + j * 16 + cc] =
            f2b(acc[i][j][q]);
}

// MODE 0: z = A@B + cond*w0c (f32) ; MODE 1/2: bout = bf16(A@B)
template <int MODE>
__global__ __launch_bounds__(256) void k_ginit(const short* __restrict__ A,
                                               const short* __restrict__ Bt,
                                               const float* __restrict__ cond,
                                               const float* __restrict__ w0c,
                                               float* __restrict__ zout,
                                               short* __restrict__ bout) {
  GEMM_PROLOGUE();
  gemm_bb<16>(A, Kp, Bt, Kp, row0, col0, lane, acc);
#pragma unroll
  for (int i = 0; i < 2; ++i)
#pragma unroll
    for (int j = 0; j < 2; ++j)
#pragma unroll
      for (int q = 0; q < 4; ++q) {
        const int row = row0 + i * 16 + rq + q;
        const int col = col0 + j * 16 + cc;
        const size_t idx = (size_t)row * Hn + col;
        if (MODE == 0)
          zout[idx] = acc[i][j][q] + cond[row] * w0c[col];
        else
          bout[idx] = f2b(acc[i][j][q]);
      }
}

// ---------------- the fused ODE kernel ----------------
// 1024 threads = 16 waves (4/SIMD for latency hiding); 32 batch rows/block;
// grid = 256 = 1 block/CU. Wave w owns the 16-col strip [w*16, w*16+16).
// Per eval, TWO gemm phases (not three):
//   B': stacked A=[h0;m0] (64 rows) @ w1T -> h1acc AND macc in one pass
//       (trace identity: tr = sum_m g1[b,m]*(m0@w1)[b,m] shares B with h1)
//   C : h1 @ w20T -> kz (z-space RK4 update)
// Trace + hsum are fragment-elementwise epilogues; no third GEMM, no w1b.
// 2 barriers/eval (C and next A touch disjoint LDS buffers).

// swizzled short-index into a [rows][256] bf16 LDS tile:
// byte ^= ((row&7)<<4)  =>  short idx ^= ((row&7)<<3). Keeps 8-short align.
__device__ __forceinline__ int swz(int row, int col) {
  return (row * 256 + col) ^ ((row & 7) << 3);
}

// acc[rb][nt] += A(16*RB x 256, swizzled LDS) @ Bt-strip. Bt row-major
// [N][256] (k contiguous, B^T). Wave covers cols [cb, cb+16*NT).
template <int RB, int NT>
__device__ __forceinline__ void gemmN(const short* __restrict__ As_,
                                      const short* __restrict__ Bt, int cb_,
                                      int cc, int g, f32x4 acc[RB][NT]) {
  const int kb0 = g * 8;
#pragma unroll
  for (int ks = 0; ks < 8; ++ks) {
    const int k = kb0 + ks * 32;
    short8v a[RB];
#pragma unroll
    for (int rb = 0; rb < RB; ++rb)
      a[rb] = *(const short8v*)(As_ + swz(rb * 16 + cc, k));
#pragma unroll
    for (int nt = 0; nt < NT; ++nt) {
      const short8v b =
          *(const short8v*)(Bt + (size_t)(cb_ + nt * 16 + cc) * 256 + k);
#pragma unroll
      for (int rb = 0; rb < RB; ++rb)
        acc[rb][nt] =
            __builtin_amdgcn_mfma_f32_16x16x32_bf16(a[rb], b, acc[rb][nt], 0, 0, 0);
    }
  }
}

constexpr int HP = 258;  // padded f32 row stride for hsum LDS

__global__ __launch_bounds__(1024) void k_mega(
    const float* __restrict__ zg, const short* __restrict__ u_g,
    const short* __restrict__ g2_g, const short* __restrict__ w1T,
    const short* __restrict__ w20T, const short* __restrict__ w2T,
    const float* __restrict__ b0, const float* __restrict__ w0t,
    const float* __restrict__ b1, const float* __restrict__ c0,
    const float* __restrict__ b2, const float* __restrict__ x,
    float* __restrict__ yout, float* __restrict__ ldout) {
  __shared__ short As[64 * 256];   // stacked [h0 (rows 0-31); m0 (rows 32-63)]
  __shared__ short h1s[32 * 256];
  __shared__ float hsum[32 * HP];
  __shared__ float red[32][16];

  const int tid = threadIdx.x;
  const int w = tid >> 6, lane = tid & 63;
  const int cc = lane & 15, g = lane >> 4, rq = g * 4;
  const int r0 = blockIdx.x * 32;
  const int cb = w * 16;  // wave's 16-col strip for the H-space GEMMs

  // per-lane column constants (one col per thread now)
  const int col = cb + cc;
  const float b0c = b0[col];
  const float w0tc = w0t[col];
  const float b1c = b1[col];
  const float c0c = c0[col];

  // element (rb,q) lives at gbase + (rb*16+q)*Hn
  const size_t gbase = (size_t)(r0 + rq) * Hn + col;

  // persistent per-thread register state (C-fragment layout)
  float z_[2][4], kza[2][4], kzp[2][4], tr_[2][4];
  unsigned u_pk[2][2], g2_pk[2][2];  // bf16 pairs packed along q
#pragma unroll
  for (int rb = 0; rb < 2; ++rb) {
    const size_t i0 = gbase + (size_t)(rb * 16) * Hn;
#pragma unroll
    for (int q = 0; q < 4; ++q) {
      z_[rb][q] = zg[i0 + (size_t)q * Hn];
      kzp[rb][q] = 0.f;
      tr_[rb][q] = 0.f;
    }
    u_pk[rb][0] = pk2(u_g[i0], u_g[i0 + Hn]);
    u_pk[rb][1] = pk2(u_g[i0 + 2 * Hn], u_g[i0 + 3 * Hn]);
    g2_pk[rb][0] = pk2(g2_g[i0], g2_g[i0 + Hn]);
    g2_pk[rb][1] = pk2(g2_g[i0 + 2 * Hn], g2_g[i0 + 3 * Hn]);
  }

  for (int i = tid; i < 32 * HP; i += 1024) hsum[i] = 0.f;
  __syncthreads();

  const f32x4 zero4 = {0.f, 0.f, 0.f, 0.f};

  for (int e = 0; e < 4 * NSTEPS; ++e) {
    const int j = e & 3, s = e >> 2;
    const float oj = (j == 0) ? 0.f : ((j == 3) ? 1.f : 0.5f);
    const float aj = (j == 0) ? 0.f : ((j == 3) ? DT : 0.5f * DT);
    const float mj = (j == 1 || j == 2) ? 2.f : 1.f;
    const float tval = ((float)s + oj) * DT;

    // ---- A: h0 = tanh(z + aj*kzp + b0 + t*w0t); m0 = (1-h0^2)*u -> stacked As
#pragma unroll
    for (int rb = 0; rb < 2; ++rb)
#pragma unroll
      for (int q = 0; q < 4; ++q) {
        const float pre = z_[rb][q] + aj * kzp[rb][q] + b0c + tval * w0tc;
        const float h = ftanh(pre);
        const float uq = (q & 1) ? upk_hi(u_pk[rb][q >> 1]) : upk_lo(u_pk[rb][q >> 1]);
        const int row = rb * 16 + rq + q;
        As[swz(row, col)] = f2b(h);
        As[swz(32 + row, col)] = f2b((1.f - h * h) * uq);
      }
    __syncthreads();

    // ---- B': [h0;m0] @ w1T in ONE pass; epilogue: h1, trace, hsum
    {
      f32x4 acc[4][1] = {{zero4}, {zero4}, {zero4}, {zero4}};
      gemmN<4, 1>(As, w1T, cb, cc, g, acc);
#pragma unroll
      for (int rb = 0; rb < 2; ++rb)
#pragma unroll
        for (int q = 0; q < 4; ++q) {
          const float v = ftanh(acc[rb][0][q] + b1c);
          const float g2q =
              (q & 1) ? upk_hi(g2_pk[rb][q >> 1]) : upk_lo(g2_pk[rb][q >> 1]);
          const float macc = acc[rb + 2][0][q];
          tr_[rb][q] += (DT6 * mj) * g2q * (1.f - v * v) * macc;
          const int row = rb * 16 + rq + q;
          h1s[swz(row, col)] = f2b(v);
          hsum[row * HP + col] += mj * v;
        }
    }
    __syncthreads();

    // ---- C: kz = h1@w20 + c0 ; RK4 z-state update (no barrier after:
    //      next A writes As only; As readers all passed the barrier above)
    {
      f32x4 acc[2][1] = {{zero4}, {zero4}};
      gemmN<2, 1>(h1s, w20T, cb, cc, g, acc);
#pragma unroll
      for (int rb = 0; rb < 2; ++rb)
#pragma unroll
        for (int q = 0; q < 4; ++q) {
          const float kzv = acc[rb][0][q] + c0c;
          if (j == 0)
            kza[rb][q] = kzv;
          else
            kza[rb][q] += mj * kzv;
          if (j < 3)
            kzp[rb][q] = kzv;
          else
            z_[rb][q] += DT6 * kza[rb][q];
        }
    }
  }

  // ---- final: y = x + DT6 * HS@w2 + b2  (sum of dt*b2 over 8 steps = b2)
#pragma unroll
  for (int rb = 0; rb < 2; ++rb)
#pragma unroll
    for (int q = 0; q < 4; ++q) {
      const int row = rb * 16 + rq + q;
      As[swz(row, col)] = f2b(hsum[row * HP + col]);
    }
  __syncthreads();
  {
    const int cb2 = w * 32;  // 512 output cols over 16 waves
    f32x4 facc[2][2] = {{zero4, zero4}, {zero4, zero4}};
    gemmN<2, 2>(As, w2T, cb2, cc, g, facc);
#pragma unroll
    for (int rb = 0; rb < 2; ++rb)
#pragma unroll
      for (int nt = 0; nt < 2; ++nt) {
        const int colo = cb2 + nt * 16 + cc;
        if (colo < Dn) {
          const float b2c = b2[colo];
#pragma unroll
          for (int q = 0; q < 4; ++q) {
            const size_t ix = (size_t)(r0 + rb * 16 + rq + q) * Dn + colo;
            yout[ix] = x[ix] + DT6 * facc[rb][nt][q] + b2c;
          }
        }
      }
  }

  // ---- trace reduction: over the 16 cc-lanes, then over 16 waves
#pragma unroll
  for (int rb = 0; rb < 2; ++rb)
#pragma unroll
    for (int q = 0; q < 4; ++q) {
      float v = tr_[rb][q];
      v += __shfl_xor(v, 1);
      v += __shfl_xor(v, 2);
      v += __shfl_xor(v, 4);
      v += __shfl_xor(v, 8);
      if (cc == 0) red[rb * 16 + rq + q][w] = v;
    }
  __syncthreads();
  if (tid < 32) {
    float t = 0.f;
#pragma unroll
    for (int ww = 0; ww < 16; ++ww) t += red[tid][ww];
    ldout[r0 + tid] = t;
  }
}

}  // namespace

extern "C" void kernel_launch(void* const* d_in, const int* in_sizes, int n_in,
                              void* d_out, int out_size, void* d_ws, size_t ws_size,
                              hipStream_t stream) {
  const float* x = (const float*)d_in[0];
  const float* cond = (const float*)d_in[1];
  const float* eps = (const float*)d_in[2];
  const float* w0 = (const float*)d_in[3];
  const float* b0 = (const float*)d_in[4];
  const float* w1 = (const float*)d_in[5];
  const float* b1 = (const float*)d_in[6];
  const float* w2 = (const float*)d_in[7];
  const float* b2 = (const float*)d_in[8];
  const float* w0c = w0 + (size_t)508 * Hn;  // cond row
  const float* w0t = w0 + (size_t)509 * Hn;  // time row

  const size_t BD = (size_t)Bn * Dn, BH = (size_t)Bn * Hn, BKp = (size_t)Bn * Kp;
  char* p = (char*)d_ws;
  auto alloc_f = [&](size_t n) { float* r = (float*)p; p += n * 4; return r; };
  auto alloc_s = [&](size_t n) { short* r = (short*)p; p += ((n * 2 + 15) & ~15ull); return r; };

  float* zg = alloc_f(BH);
  float* c0 = alloc_f(256);
  short* xp = alloc_s(BKp);
  short* epsp = alloc_s(BKp);
  short* u_g = alloc_s(BH);
  short* g2_g = alloc_s(BH);
  short* w0T = alloc_s(256 * 512);
  short* w1T = alloc_s(256 * 256);
  short* w2b = alloc_s(256 * 512);
  short* w2T = alloc_s(512 * 256);
  short* w20T = alloc_s(256 * 256);

  float* yout = (float*)d_out;        // [B, D]
  float* ldout = (float*)d_out + BD;  // [B]

  const dim3 blk(256);
  const dim3 gH(Hn / 64, Bn / 64);  // (4,128)
  const dim3 gW(4, 4);

  // ---- setup (weights + z/u/g2 precompute) ----
  k_cast_bf<<<4096, blk, 0, stream>>>(x, Bn, Dn, xp, Kp);
  k_cast_bf<<<4096, blk, 0, stream>>>(eps, Bn, Dn, epsp, Kp);
  k_cast_bf<<<512, blk, 0, stream>>>(w2, Hn, Dn, w2b, Kp);
  k_transpose_bf<<<256, blk, 0, stream>>>(w1, Hn, Hn, w1T, Hn, Hn);
  k_transpose_bf<<<512, blk, 0, stream>>>(w0, Dn, Hn, w0T, Hn, Kp);
  k_transpose_bf<<<512, blk, 0, stream>>>(w2, Hn, Dn, w2T, Kp, Hn);
  k_c0<<<1, blk, 0, stream>>>(w0, b2, c0);
  k_w20t<<<gW, blk, 0, stream>>>(w0T, w2b, w20T);
  k_ginit<0><<<gH, blk, 0, stream>>>(xp, w0T, cond, w0c, zg, nullptr);
  k_ginit<1><<<gH, blk, 0, stream>>>(epsp, w0T, nullptr, nullptr, nullptr, u_g);
  k_ginit<2><<<gH, blk, 0, stream>>>(epsp, w2b, nullptr, nullptr, nullptr, g2_g);

  // ---- the whole ODE in one kernel ----
  k_mega<<<dim3(Bn / 32), dim3(1024), 0, stream>>>(zg, u_g, g2_g, w1T, w20T,
                                                   w2T, b0, w0t, b1, c0, b2, x,
                                                   yout, ldout);
}